// Round 3
// baseline (821.007 us; speedup 1.0000x reference)
//
#include <hip/hip_runtime.h>
#include <math.h>
#include <stdint.h>

// ---------------------------------------------------------------------------
// IntraModalContrastive loss. Round 9:
//  - row_loss_kernel: register-retention single-pass over S. Each thread
//    loads its 16 elements ONCE (2x uint4), keeps them as fp32 in VGPRs
//    across the histogram barrier, and reuses them for the exp-sum pass.
//    Halves the LLC read traffic (was 2x 64 MB per dispatch at ~1.9 TB/s,
//    the observed ceiling).
//  - GEMM unchanged from Round 8 (128x128, BK=64, dbuf 2-phase, src-side
//    XOR swizzle, 1 barrier/K-tile).
// ---------------------------------------------------------------------------

typedef __attribute__((ext_vector_type(4))) float  floatx4;
typedef __attribute__((ext_vector_type(8))) __bf16 bf16x8;

__device__ __forceinline__ unsigned short f2bf(float f)
{
    unsigned u = __float_as_uint(f);
    unsigned r = (u + 0x7FFFu + ((u >> 16) & 1u)) >> 16;
    return (unsigned short)r;
}

__device__ __forceinline__ float bf2f(unsigned short u)
{
    return __uint_as_float((unsigned)u << 16);
}

__device__ __forceinline__ void gld_lds16(const void* g, void* l)
{
    __builtin_amdgcn_global_load_lds(
        (const __attribute__((address_space(1))) void*)g,
        (__attribute__((address_space(3))) void*)(uint32_t)(uintptr_t)l,
        16, 0, 0);
}

#define EPW 136   // epilogue LDS row stride in shorts (272 B, 16B-aligned)

// Stage one 128x64 bf16 tile (16 KB) global -> LDS, source-side swizzled:
// LDS chunk position p = row*8 + s holds global column-chunk c = s ^ (row&7).
// Dest is linear (wave-uniform base + lane*16) as global_load_lds requires.
__device__ __forceinline__ void stage_tile(
    const unsigned short* __restrict__ g, int ld, int k0,
    unsigned short* lds, int t)
{
#pragma unroll
    for (int it = 0; it < 4; ++it) {
        const int row = it * 32 + (t >> 3);
        const int c   = (t & 7) ^ ((t >> 3) & 7);     // == (t&7) ^ (row&7)
        gld_lds16(g + (size_t)row * ld + k0 + c * 8,
                  lds + (it * 256 + t) * 8);
    }
}

// ---------- bf16 MFMA GEMM: 128x128 tile, 256 thr, BK=64, dbuf ------------
// C[M,N] = ep(scale*(A @ B^T) + bias); A: MxK bf16 (lda), B: NxK bf16 (ldb).
// grid.x == (M/128)*(N/128), divisible by 8; M/128 divisible by 4;
// K divisible by 64.
__global__ __launch_bounds__(256) void gemm_bt_mfma(
    const unsigned short* __restrict__ A, int lda,
    const unsigned short* __restrict__ B, int ldb,
    unsigned short* __restrict__ C, int ldc, int M, int N, int K,
    const float* __restrict__ bias, int relu, float scale)
{
    // buf0: A [0,8192) B [8192,16384); buf1: A [16384,24576) B [24576,32768)
    // epilogue reuses [0, 128*EPW). Total = 65536 B (2 blocks/CU).
    __shared__ __align__(16) unsigned short smem[32768];

    const int num_n = N >> 7;
    const int per   = gridDim.x >> 3;
    const int pid   = blockIdx.x;
    const int npid  = (pid & 7) * per + (pid >> 3);   // XCD-contiguous
    const int width = 4 * num_n;
    const int group = npid / width;
    const int rem   = npid - group * width;
    const int pm    = group * 4 + (rem & 3);
    const int pn    = rem >> 2;

    const int t    = threadIdx.x;
    const int lane = t & 63;
    const int w    = t >> 6;        // 0..3
    const int wr   = w >> 1;        // 0..1 (64-row band)
    const int wc   = w & 1;         // 0..1 (64-col band)
    const size_t m0 = (size_t)pm * 128;
    const size_t n0 = (size_t)pn * 128;

    floatx4 acc[4][4] = {};

    const unsigned short* Abase = A + m0 * (size_t)lda;
    const unsigned short* Bbase = B + n0 * (size_t)ldb;

    // Loop-invariant swizzled fragment offsets (shorts, relative to buf base).
    // Fragment (row r, k-chunk c = ks*4 + lane>>4) lives at r*64 + (c^(r&7))*8.
    int aoff[4][2], boff[4][2];
#pragma unroll
    for (int i = 0; i < 4; ++i) {
        const int ra = wr * 64 + i * 16 + (lane & 15);
        const int rb = wc * 64 + i * 16 + (lane & 15);
#pragma unroll
        for (int ks = 0; ks < 2; ++ks) {
            const int cc = ks * 4 + (lane >> 4);
            aoff[i][ks] = ra * 64 + ((cc ^ (ra & 7)) << 3);
            boff[i][ks] = rb * 64 + ((cc ^ (rb & 7)) << 3);
        }
    }

    const int NT = K >> 6;

    // prologue: stage K-tile 0 into buf0, drain, barrier
    stage_tile(Abase, lda, 0, smem, t);
    stage_tile(Bbase, ldb, 0, smem + 8192, t);
    __syncthreads();

    int cur = 0;
    for (int kt = 0; kt < NT; ++kt) {
        // issue next tile's staging FIRST -> latency hides under compute
        if (kt + 1 < NT) {
            unsigned short* nb = smem + (cur ^ 1) * 16384;
            stage_tile(Abase, lda, (kt + 1) << 6, nb, t);
            stage_tile(Bbase, ldb, (kt + 1) << 6, nb + 8192, t);
        }

        const unsigned short* As = smem + cur * 16384;
        const unsigned short* Bs = As + 8192;

        bf16x8 af[4][2], bfr[4][2];
#pragma unroll
        for (int i = 0; i < 4; ++i) {
#pragma unroll
            for (int ks = 0; ks < 2; ++ks) {
                af[i][ks]  = *(const bf16x8*)(As + aoff[i][ks]);
                bfr[i][ks] = *(const bf16x8*)(Bs + boff[i][ks]);
            }
        }
#pragma unroll
        for (int i = 0; i < 4; ++i)
#pragma unroll
            for (int j = 0; j < 4; ++j)
#pragma unroll
                for (int ks = 0; ks < 2; ++ks)
                    acc[i][j] = __builtin_amdgcn_mfma_f32_16x16x32_bf16(
                        af[i][ks], bfr[j][ks], acc[i][j], 0, 0, 0);

        __syncthreads();   // drains prefetch vmcnt + barrier (once per K-tile)
        cur ^= 1;
    }

    // --- epilogue: one 128-row pass through LDS, coalesced uint4 stores ---
    const int col   = lane & 15;
    const int rquad = (lane >> 4) * 4;
#pragma unroll
    for (int j = 0; j < 4; ++j) {
        const int lc = wc * 64 + j * 16 + col;
        const float bv = bias ? bias[n0 + lc] : 0.0f;
#pragma unroll
        for (int i = 0; i < 4; ++i) {
            const int lr0 = wr * 64 + i * 16 + rquad;
#pragma unroll
            for (int r = 0; r < 4; ++r) {
                float v = acc[i][j][r] * scale + bv;
                if (relu) v = fmaxf(v, 0.0f);
                smem[(lr0 + r) * EPW + lc] = f2bf(v);
            }
        }
    }
    __syncthreads();
#pragma unroll
    for (int h = 0; h < 2; ++h) {
        const int cr = h * 64 + (t >> 2);   // 0..127
        const int cq = t & 3;
#pragma unroll
        for (int q = 0; q < 4; ++q) {
            const int chunk = cq + q * 4;           // 0..15
            uint4 v = *(const uint4*)(smem + cr * EPW + chunk * 8);
            *(uint4*)(C + (m0 + cr) * (size_t)ldc + n0 + chunk * 8) = v;
        }
    }
}

// ---------- elementwise fp32 -> bf16 cast -----------------------------------
__global__ __launch_bounds__(256) void cast_bf16_kernel(
    const float* __restrict__ in, unsigned short* __restrict__ out, int n4)
{
    const int i = blockIdx.x * 256 + threadIdx.x;
    if (i < n4) {
        float4 v = *(const float4*)(in + (size_t)i * 4);
        ushort4 o;
        o.x = f2bf(v.x); o.y = f2bf(v.y); o.z = f2bf(v.z); o.w = f2bf(v.w);
        *(ushort4*)(out + (size_t)i * 4) = o;
    }
}

// ---------- transpose + cast: W[K,N] fp32 -> WT[N,K] bf16 -------------------
__global__ __launch_bounds__(256) void transpose_cast_kernel(
    const float* __restrict__ W, unsigned short* __restrict__ WT, int K, int N)
{
    __shared__ float tile[32][33];
    const int k0 = blockIdx.y * 32;
    const int n0 = blockIdx.x * 32;
    const int tr = threadIdx.x >> 3;
    const int tc = (threadIdx.x & 7) * 4;

    float4 v = *(const float4*)(W + (size_t)(k0 + tr) * N + n0 + tc);
    tile[tr][tc + 0] = v.x;
    tile[tr][tc + 1] = v.y;
    tile[tr][tc + 2] = v.z;
    tile[tr][tc + 3] = v.w;
    __syncthreads();

    ushort4 o;
    o.x = f2bf(tile[tc + 0][tr]);
    o.y = f2bf(tile[tc + 1][tr]);
    o.z = f2bf(tile[tc + 2][tr]);
    o.w = f2bf(tile[tc + 3][tr]);
    *(ushort4*)(WT + (size_t)(n0 + tr) * K + k0 + tc) = o;
}

// ---------- row L2-normalize, bf16 in-place, width 512 ----------------------
__global__ __launch_bounds__(128) void normalize_bf16_kernel(
    unsigned short* __restrict__ X)
{
    const int r = blockIdx.x;
    const int t = threadIdx.x;
    unsigned short* row = X + (size_t)r * 512;
    ushort4 u = *(const ushort4*)(row + t * 4);
    float x0 = bf2f(u.x), x1 = bf2f(u.y), x2 = bf2f(u.z), x3 = bf2f(u.w);
    float ss = x0 * x0 + x1 * x1 + x2 * x2 + x3 * x3;
#pragma unroll
    for (int off = 32; off > 0; off >>= 1) ss += __shfl_down(ss, off, 64);
    __shared__ float sred[2];
    if ((t & 63) == 0) sred[t >> 6] = ss;
    __syncthreads();
    float inv = 1.0f / sqrtf(sred[0] + sred[1]);
    ushort4 o;
    o.x = f2bf(x0 * inv); o.y = f2bf(x1 * inv);
    o.z = f2bf(x2 * inv); o.w = f2bf(x3 * inv);
    *(ushort4*)(row + t * 4) = o;
}

// ---------- per-row mining + loss (v4: single S read, reg retention) --------
__global__ __launch_bounds__(512) void row_loss_kernel(
    const unsigned short* __restrict__ S, int row_base,
    const float* __restrict__ mw, int midx, float* __restrict__ accum)
{
    __shared__ unsigned hist[4096];         // 16 KB
    __shared__ unsigned wtot[8];
    __shared__ float fred[8];
    __shared__ unsigned sh_b;
    __shared__ float sh_diag;

    const int t    = threadIdx.x;
    const int lane = t & 63;
    const int wv   = t >> 6;
    const int i    = row_base + blockIdx.x;     // diag column index
    const unsigned short* Srow = S + (size_t)blockIdx.x * 8192;

    for (int b = t; b < 4096; b += 512) hist[b] = 0;

    // single global read: this thread's 16 elements (columns t*8 .. t*8+7
    // and t*8+4096 .. t*8+4103), kept as fp32 in registers.
    const uint4 raw0 = *(const uint4*)(Srow + t * 8);
    const uint4 raw1 = *(const uint4*)(Srow + t * 8 + 4096);
    float sv[16];
    {
        const unsigned short* e0 = (const unsigned short*)&raw0;
        const unsigned short* e1 = (const unsigned short*)&raw1;
#pragma unroll
        for (int q = 0; q < 8; ++q) {
            sv[q]     = bf2f(e0[q]);
            sv[8 + q] = bf2f(e1[q]);
        }
    }
    __syncthreads();     // hist zeroed

#pragma unroll
    for (int q = 0; q < 16; ++q) {
        const int j = (q < 8) ? (t * 8 + q) : (t * 8 + 4096 + (q - 8));
        const float s = sv[q];
        if (j != i && s <= 9.0f) {
            int k = (int)((s + 10.25f) * 200.0f);
            k = k < 1 ? 1 : (k > 4095 ? 4095 : k);
            atomicAdd(&hist[k], 1u);
        }
    }
    __syncthreads();

    unsigned local = 0;
#pragma unroll
    for (int q = 0; q < 8; ++q) local += hist[t * 8 + q];
    unsigned suf = local;
#pragma unroll
    for (int off = 1; off < 64; off <<= 1) {
        unsigned v = __shfl_down(suf, off, 64);
        if (lane + off < 64) suf += v;
    }
    if (lane == 0) wtot[wv] = suf;
    __syncthreads();
    unsigned wsuf = 0;
#pragma unroll
    for (int q = 0; q < 8; ++q) wsuf += (q > wv) ? wtot[q] : 0u;
    suf += wsuf;

    const unsigned target = 4096;
    const unsigned above  = suf - local;
    if (suf >= target && above < target) {
        unsigned cum = above;
        int bsel = t * 8;
#pragma unroll
        for (int q = 7; q >= 0; --q) {
            unsigned c = hist[t * 8 + q];
            if (cum + c >= target) { bsel = t * 8 + q; break; }
            cum += c;
        }
        sh_b = (unsigned)bsel;
    }
    if (t == 0 && suf < target) sh_b = 1u;
    __syncthreads();
    const unsigned bsel = sh_b;

    float lsum = 0.0f;
#pragma unroll
    for (int q = 0; q < 16; ++q) {
        const int j = (q < 8) ? (t * 8 + q) : (t * 8 + 4096 + (q - 8));
        const float s = sv[q];
        bool diag  = (j == i);
        bool noise = (!diag && s > 9.0f);
        int k = (int)((s + 10.25f) * 200.0f);
        k = k < 1 ? 1 : (k > 4095 ? 4095 : k);
        bool hard = !diag && !noise && ((unsigned)k >= bsel);
        float wgt = noise ? 0.5f : (hard ? 1.5f : 1.0f);
        float ws = s * wgt;
        if (diag) sh_diag = ws;
        lsum += __expf(ws - 16.0f);
    }
#pragma unroll
    for (int off = 32; off > 0; off >>= 1)
        lsum += __shfl_down(lsum, off, 64);
    if (lane == 0) fred[wv] = lsum;
    __syncthreads();
    if (t == 0) {
        float total = 0.0f;
#pragma unroll
        for (int q = 0; q < 8; ++q) total += fred[q];
        float lse = 16.0f + logf(total);
        float ce = lse - sh_diag;
        atomicAdd(&accum[midx], ce * mw[(size_t)i * 2 + midx]);
    }
}

__global__ void zero_kernel(float* __restrict__ accum)
{
    if (threadIdx.x < 2) accum[threadIdx.x] = 0.0f;
}

__global__ void finalize_kernel(const float* __restrict__ accum,
                                float* __restrict__ out)
{
    out[0] = (accum[0] + accum[1]) * (1.0f / 16384.0f);
}

// ---------------------------------------------------------------------------
extern "C" void kernel_launch(void* const* d_in, const int* in_sizes, int n_in,
                              void* d_out, int out_size, void* d_ws, size_t ws_size,
                              hipStream_t stream)
{
    (void)in_sizes; (void)n_in; (void)out_size; (void)ws_size;

    const float* id_emb = (const float*)d_in[0];
    const float* feats[2] = { (const float*)d_in[1], (const float*)d_in[2] };
    const float* mw     = (const float*)d_in[3];
    const float* Wa[2]  = { (const float*)d_in[4],  (const float*)d_in[6]  };
    const float* ba[2]  = { (const float*)d_in[5],  (const float*)d_in[7]  };
    const float* W1[2]  = { (const float*)d_in[8],  (const float*)d_in[12] };
    const float* b1[2]  = { (const float*)d_in[9],  (const float*)d_in[13] };
    const float* W2[2]  = { (const float*)d_in[10], (const float*)d_in[14] };
    const float* b2[2]  = { (const float*)d_in[11], (const float*)d_in[15] };
    const int    Fdim[2] = { 768, 2048 };

    // Layout: X is NOT aliased (id half persists across modalities);
    // S (64 MB) aliases featb+H (both dead during the sim phase).
    char* p = (char*)d_ws;
    unsigned short* WaT   = (unsigned short*)p; p += (size_t)1024 * 2048 * 2;  //  4 MB
    unsigned short* W1T   = (unsigned short*)p; p += (size_t)1024 * 1024 * 2;  //  2 MB
    unsigned short* W2T   = (unsigned short*)p; p += (size_t)512  * 1024 * 2;  //  1 MB
    unsigned short* X     = (unsigned short*)p; p += (size_t)16384 * 1024 * 2; // 32 MB
    unsigned short* featb = (unsigned short*)p; p += (size_t)8192 * 2048 * 2;  // 32 MB
    unsigned short* H     = (unsigned short*)p; p += (size_t)16384 * 1024 * 2; // 32 MB
    unsigned short* PB    = (unsigned short*)p; p += (size_t)16384 * 512  * 2; // 16 MB
    float*          accum = (float*)p;
    unsigned short* S     = featb;               // 4096x8192 bf16 = 64 MB

    zero_kernel<<<1, 64, 0, stream>>>(accum);

    // id embeddings -> bf16 lower half of X, once (X never aliased)
    cast_bf16_kernel<<<(8192 * 1024 / 4 + 255) / 256, 256, 0, stream>>>(
        id_emb, X + (size_t)8192 * 1024, 8192 * 1024 / 4);

    for (int m = 0; m < 2; ++m) {
        const int F = Fdim[m];

        cast_bf16_kernel<<<(8192 * F / 4 + 255) / 256, 256, 0, stream>>>(
            feats[m], featb, 8192 * F / 4);
        transpose_cast_kernel<<<dim3(1024 / 32, F / 32), 256, 0, stream>>>(
            Wa[m], WaT, F, 1024);
        transpose_cast_kernel<<<dim3(1024 / 32, 1024 / 32), 256, 0, stream>>>(
            W1[m], W1T, 1024, 1024);
        transpose_cast_kernel<<<dim3(512 / 32, 1024 / 32), 256, 0, stream>>>(
            W2[m], W2T, 1024, 512);

        // X[0:8192] = feat @ Wa + ba   (8192 x 1024, bf16)
        gemm_bt_mfma<<<(8192 / 128) * (1024 / 128), 256, 0, stream>>>(
            featb, F, WaT, F, X, 1024, 8192, 1024, F, ba[m], 0, 1.0f);

        // H = relu(X @ W1 + b1)        (16384 x 1024, bf16)
        gemm_bt_mfma<<<(16384 / 128) * (1024 / 128), 256, 0, stream>>>(
            X, 1024, W1T, 1024, H, 1024, 16384, 1024, 1024, b1[m], 1, 1.0f);
        // PB = H @ W2 + b2             (16384 x 512, bf16)
        gemm_bt_mfma<<<(16384 / 128) * (512 / 128), 256, 0, stream>>>(
            H, 1024, W2T, 1024, PB, 512, 16384, 512, 1024, b2[m], 0, 1.0f);
        // normalize in place           (modal rows 0:8192, id rows 8192:)
        normalize_bf16_kernel<<<16384, 128, 0, stream>>>(PB);

        const unsigned short* mproj = PB;
        const unsigned short* iproj = PB + (size_t)8192 * 512;

        for (int c = 0; c < 2; ++c) {
            // S = 10 * id_proj[chunk 4096] @ modal_proj^T  (4096 x 8192 bf16)
            gemm_bt_mfma<<<(4096 / 128) * (8192 / 128), 256, 0, stream>>>(
                iproj + (size_t)c * 4096 * 512, 512, mproj, 512,
                S, 8192, 4096, 8192, 512, nullptr, 0, 10.0f);
            row_loss_kernel<<<4096, 512, 0, stream>>>(
                S, c * 4096, mw, m, accum);
        }
    }

    finalize_kernel<<<1, 1, 0, stream>>>(accum, (float*)d_out);
}

// Round 4
// 760.945 us; speedup vs baseline: 1.0789x; 1.0789x over previous
//
#include <hip/hip_runtime.h>
#include <math.h>
#include <stdint.h>

// ---------------------------------------------------------------------------
// IntraModalContrastive loss. Round 10:
//  - row_loss_kernel v5: 256-thr blocks (4 waves), 32 elems/thread kept as
//    RAW bf16 in 8 VGPRs (extracted on the fly) -> low VGPR, up to 8
//    blocks/CU (was 2) to overlap the barrier/latency chain.
//  - accum atomics spread across 64 slots per modality (was 4096 blocks ->
//    1 address, a TCC same-address serialization funnel).
//  - GEMM unchanged from Round 8 (128x128, BK=64, dbuf 2-phase, src-side
//    XOR swizzle, 1 barrier/K-tile).
// ---------------------------------------------------------------------------

typedef __attribute__((ext_vector_type(4))) float  floatx4;
typedef __attribute__((ext_vector_type(8))) __bf16 bf16x8;

__device__ __forceinline__ unsigned short f2bf(float f)
{
    unsigned u = __float_as_uint(f);
    unsigned r = (u + 0x7FFFu + ((u >> 16) & 1u)) >> 16;
    return (unsigned short)r;
}

__device__ __forceinline__ float bf2f(unsigned short u)
{
    return __uint_as_float((unsigned)u << 16);
}

__device__ __forceinline__ void gld_lds16(const void* g, void* l)
{
    __builtin_amdgcn_global_load_lds(
        (const __attribute__((address_space(1))) void*)g,
        (__attribute__((address_space(3))) void*)(uint32_t)(uintptr_t)l,
        16, 0, 0);
}

#define EPW 136   // epilogue LDS row stride in shorts (272 B, 16B-aligned)

// Stage one 128x64 bf16 tile (16 KB) global -> LDS, source-side swizzled:
// LDS chunk position p = row*8 + s holds global column-chunk c = s ^ (row&7).
// Dest is linear (wave-uniform base + lane*16) as global_load_lds requires.
__device__ __forceinline__ void stage_tile(
    const unsigned short* __restrict__ g, int ld, int k0,
    unsigned short* lds, int t)
{
#pragma unroll
    for (int it = 0; it < 4; ++it) {
        const int row = it * 32 + (t >> 3);
        const int c   = (t & 7) ^ ((t >> 3) & 7);     // == (t&7) ^ (row&7)
        gld_lds16(g + (size_t)row * ld + k0 + c * 8,
                  lds + (it * 256 + t) * 8);
    }
}

// ---------- bf16 MFMA GEMM: 128x128 tile, 256 thr, BK=64, dbuf ------------
// C[M,N] = ep(scale*(A @ B^T) + bias); A: MxK bf16 (lda), B: NxK bf16 (ldb).
// grid.x == (M/128)*(N/128), divisible by 8; M/128 divisible by 4;
// K divisible by 64.
__global__ __launch_bounds__(256) void gemm_bt_mfma(
    const unsigned short* __restrict__ A, int lda,
    const unsigned short* __restrict__ B, int ldb,
    unsigned short* __restrict__ C, int ldc, int M, int N, int K,
    const float* __restrict__ bias, int relu, float scale)
{
    // buf0: A [0,8192) B [8192,16384); buf1: A [16384,24576) B [24576,32768)
    // epilogue reuses [0, 128*EPW). Total = 65536 B (2 blocks/CU).
    __shared__ __align__(16) unsigned short smem[32768];

    const int num_n = N >> 7;
    const int per   = gridDim.x >> 3;
    const int pid   = blockIdx.x;
    const int npid  = (pid & 7) * per + (pid >> 3);   // XCD-contiguous
    const int width = 4 * num_n;
    const int group = npid / width;
    const int rem   = npid - group * width;
    const int pm    = group * 4 + (rem & 3);
    const int pn    = rem >> 2;

    const int t    = threadIdx.x;
    const int lane = t & 63;
    const int w    = t >> 6;        // 0..3
    const int wr   = w >> 1;        // 0..1 (64-row band)
    const int wc   = w & 1;         // 0..1 (64-col band)
    const size_t m0 = (size_t)pm * 128;
    const size_t n0 = (size_t)pn * 128;

    floatx4 acc[4][4] = {};

    const unsigned short* Abase = A + m0 * (size_t)lda;
    const unsigned short* Bbase = B + n0 * (size_t)ldb;

    // Loop-invariant swizzled fragment offsets (shorts, relative to buf base).
    // Fragment (row r, k-chunk c = ks*4 + lane>>4) lives at r*64 + (c^(r&7))*8.
    int aoff[4][2], boff[4][2];
#pragma unroll
    for (int i = 0; i < 4; ++i) {
        const int ra = wr * 64 + i * 16 + (lane & 15);
        const int rb = wc * 64 + i * 16 + (lane & 15);
#pragma unroll
        for (int ks = 0; ks < 2; ++ks) {
            const int cc = ks * 4 + (lane >> 4);
            aoff[i][ks] = ra * 64 + ((cc ^ (ra & 7)) << 3);
            boff[i][ks] = rb * 64 + ((cc ^ (rb & 7)) << 3);
        }
    }

    const int NT = K >> 6;

    // prologue: stage K-tile 0 into buf0, drain, barrier
    stage_tile(Abase, lda, 0, smem, t);
    stage_tile(Bbase, ldb, 0, smem + 8192, t);
    __syncthreads();

    int cur = 0;
    for (int kt = 0; kt < NT; ++kt) {
        // issue next tile's staging FIRST -> latency hides under compute
        if (kt + 1 < NT) {
            unsigned short* nb = smem + (cur ^ 1) * 16384;
            stage_tile(Abase, lda, (kt + 1) << 6, nb, t);
            stage_tile(Bbase, ldb, (kt + 1) << 6, nb + 8192, t);
        }

        const unsigned short* As = smem + cur * 16384;
        const unsigned short* Bs = As + 8192;

        bf16x8 af[4][2], bfr[4][2];
#pragma unroll
        for (int i = 0; i < 4; ++i) {
#pragma unroll
            for (int ks = 0; ks < 2; ++ks) {
                af[i][ks]  = *(const bf16x8*)(As + aoff[i][ks]);
                bfr[i][ks] = *(const bf16x8*)(Bs + boff[i][ks]);
            }
        }
#pragma unroll
        for (int i = 0; i < 4; ++i)
#pragma unroll
            for (int j = 0; j < 4; ++j)
#pragma unroll
                for (int ks = 0; ks < 2; ++ks)
                    acc[i][j] = __builtin_amdgcn_mfma_f32_16x16x32_bf16(
                        af[i][ks], bfr[j][ks], acc[i][j], 0, 0, 0);

        __syncthreads();   // drains prefetch vmcnt + barrier (once per K-tile)
        cur ^= 1;
    }

    // --- epilogue: one 128-row pass through LDS, coalesced uint4 stores ---
    const int col   = lane & 15;
    const int rquad = (lane >> 4) * 4;
#pragma unroll
    for (int j = 0; j < 4; ++j) {
        const int lc = wc * 64 + j * 16 + col;
        const float bv = bias ? bias[n0 + lc] : 0.0f;
#pragma unroll
        for (int i = 0; i < 4; ++i) {
            const int lr0 = wr * 64 + i * 16 + rquad;
#pragma unroll
            for (int r = 0; r < 4; ++r) {
                float v = acc[i][j][r] * scale + bv;
                if (relu) v = fmaxf(v, 0.0f);
                smem[(lr0 + r) * EPW + lc] = f2bf(v);
            }
        }
    }
    __syncthreads();
#pragma unroll
    for (int h = 0; h < 2; ++h) {
        const int cr = h * 64 + (t >> 2);   // 0..127
        const int cq = t & 3;
#pragma unroll
        for (int q = 0; q < 4; ++q) {
            const int chunk = cq + q * 4;           // 0..15
            uint4 v = *(const uint4*)(smem + cr * EPW + chunk * 8);
            *(uint4*)(C + (m0 + cr) * (size_t)ldc + n0 + chunk * 8) = v;
        }
    }
}

// ---------- elementwise fp32 -> bf16 cast -----------------------------------
__global__ __launch_bounds__(256) void cast_bf16_kernel(
    const float* __restrict__ in, unsigned short* __restrict__ out, int n4)
{
    const int i = blockIdx.x * 256 + threadIdx.x;
    if (i < n4) {
        float4 v = *(const float4*)(in + (size_t)i * 4);
        ushort4 o;
        o.x = f2bf(v.x); o.y = f2bf(v.y); o.z = f2bf(v.z); o.w = f2bf(v.w);
        *(ushort4*)(out + (size_t)i * 4) = o;
    }
}

// ---------- transpose + cast: W[K,N] fp32 -> WT[N,K] bf16 -------------------
__global__ __launch_bounds__(256) void transpose_cast_kernel(
    const float* __restrict__ W, unsigned short* __restrict__ WT, int K, int N)
{
    __shared__ float tile[32][33];
    const int k0 = blockIdx.y * 32;
    const int n0 = blockIdx.x * 32;
    const int tr = threadIdx.x >> 3;
    const int tc = (threadIdx.x & 7) * 4;

    float4 v = *(const float4*)(W + (size_t)(k0 + tr) * N + n0 + tc);
    tile[tr][tc + 0] = v.x;
    tile[tr][tc + 1] = v.y;
    tile[tr][tc + 2] = v.z;
    tile[tr][tc + 3] = v.w;
    __syncthreads();

    ushort4 o;
    o.x = f2bf(tile[tc + 0][tr]);
    o.y = f2bf(tile[tc + 1][tr]);
    o.z = f2bf(tile[tc + 2][tr]);
    o.w = f2bf(tile[tc + 3][tr]);
    *(ushort4*)(WT + (size_t)(n0 + tr) * K + k0 + tc) = o;
}

// ---------- row L2-normalize, bf16 in-place, width 512 ----------------------
__global__ __launch_bounds__(128) void normalize_bf16_kernel(
    unsigned short* __restrict__ X)
{
    const int r = blockIdx.x;
    const int t = threadIdx.x;
    unsigned short* row = X + (size_t)r * 512;
    ushort4 u = *(const ushort4*)(row + t * 4);
    float x0 = bf2f(u.x), x1 = bf2f(u.y), x2 = bf2f(u.z), x3 = bf2f(u.w);
    float ss = x0 * x0 + x1 * x1 + x2 * x2 + x3 * x3;
#pragma unroll
    for (int off = 32; off > 0; off >>= 1) ss += __shfl_down(ss, off, 64);
    __shared__ float sred[2];
    if ((t & 63) == 0) sred[t >> 6] = ss;
    __syncthreads();
    float inv = 1.0f / sqrtf(sred[0] + sred[1]);
    ushort4 o;
    o.x = f2bf(x0 * inv); o.y = f2bf(x1 * inv);
    o.z = f2bf(x2 * inv); o.w = f2bf(x3 * inv);
    *(ushort4*)(row + t * 4) = o;
}

// ---------- per-row mining + loss (v5: 256 thr, raw-reg retention) ----------
// accum is a 2x64 float array; each block adds into slot [midx*64 + blk&63].
__global__ __launch_bounds__(256, 8) void row_loss_kernel(
    const unsigned short* __restrict__ S, int row_base,
    const float* __restrict__ mw, int midx, float* __restrict__ accum)
{
    __shared__ unsigned hist[4096];         // 16 KB
    __shared__ unsigned wtot[4];
    __shared__ float fred[4];
    __shared__ unsigned sh_b;
    __shared__ float sh_diag;

    const int t    = threadIdx.x;           // 0..255
    const int lane = t & 63;
    const int wv   = t >> 6;                // 0..3
    const int i    = row_base + blockIdx.x; // diag column index
    const unsigned short* Srow = S + (size_t)blockIdx.x * 8192;

    for (int b = t; b < 4096; b += 256) hist[b] = 0;

    // single global read: 32 elements as raw bf16 in 8 VGPRs.
    // segment seg (0..3) covers columns seg*2048 + t*8 .. +7.
    uint4 raw[4];
#pragma unroll
    for (int seg = 0; seg < 4; ++seg)
        raw[seg] = *(const uint4*)(Srow + seg * 2048 + t * 8);
    __syncthreads();     // hist zeroed

#pragma unroll
    for (int seg = 0; seg < 4; ++seg) {
        const unsigned short* e = (const unsigned short*)&raw[seg];
#pragma unroll
        for (int q = 0; q < 8; ++q) {
            const int j = seg * 2048 + t * 8 + q;
            const float s = bf2f(e[q]);
            if (j != i && s <= 9.0f) {
                int k = (int)((s + 10.25f) * 200.0f);
                k = k < 1 ? 1 : (k > 4095 ? 4095 : k);
                atomicAdd(&hist[k], 1u);
            }
        }
    }
    __syncthreads();

    // suffix-sum over 4096 bins; thread t owns bins [t*16, t*16+16)
    unsigned local = 0;
#pragma unroll
    for (int q = 0; q < 16; ++q) local += hist[t * 16 + q];
    unsigned suf = local;
#pragma unroll
    for (int off = 1; off < 64; off <<= 1) {
        unsigned v = __shfl_down(suf, off, 64);
        if (lane + off < 64) suf += v;
    }
    if (lane == 0) wtot[wv] = suf;
    __syncthreads();
    unsigned wsuf = 0;
#pragma unroll
    for (int q = 0; q < 4; ++q) wsuf += (q > wv) ? wtot[q] : 0u;
    suf += wsuf;

    const unsigned target = 4096;
    const unsigned above  = suf - local;
    if (suf >= target && above < target) {
        unsigned cum = above;
        int bsel = t * 16;
#pragma unroll
        for (int q = 15; q >= 0; --q) {
            unsigned c = hist[t * 16 + q];
            if (cum + c >= target) { bsel = t * 16 + q; break; }
            cum += c;
        }
        sh_b = (unsigned)bsel;
    }
    if (t == 0 && suf < target) sh_b = 1u;
    __syncthreads();
    const unsigned bsel = sh_b;

    float lsum = 0.0f;
#pragma unroll
    for (int seg = 0; seg < 4; ++seg) {
        const unsigned short* e = (const unsigned short*)&raw[seg];
#pragma unroll
        for (int q = 0; q < 8; ++q) {
            const int j = seg * 2048 + t * 8 + q;
            const float s = bf2f(e[q]);
            bool diag  = (j == i);
            bool noise = (!diag && s > 9.0f);
            int k = (int)((s + 10.25f) * 200.0f);
            k = k < 1 ? 1 : (k > 4095 ? 4095 : k);
            bool hard = !diag && !noise && ((unsigned)k >= bsel);
            float wgt = noise ? 0.5f : (hard ? 1.5f : 1.0f);
            float ws = s * wgt;
            if (diag) sh_diag = ws;
            lsum += __expf(ws - 16.0f);
        }
    }
#pragma unroll
    for (int off = 32; off > 0; off >>= 1)
        lsum += __shfl_down(lsum, off, 64);
    if (lane == 0) fred[wv] = lsum;
    __syncthreads();
    if (t == 0) {
        float total = fred[0] + fred[1] + fred[2] + fred[3];
        float lse = 16.0f + logf(total);
        float ce = lse - sh_diag;
        atomicAdd(&accum[midx * 64 + (blockIdx.x & 63)],
                  ce * mw[(size_t)i * 2 + midx]);
    }
}

__global__ void zero_kernel(float* __restrict__ accum)
{
    if (threadIdx.x < 128) accum[threadIdx.x] = 0.0f;
}

__global__ void finalize_kernel(const float* __restrict__ accum,
                                float* __restrict__ out)
{
    float s = 0.0f;
    for (int q = 0; q < 128; ++q) s += accum[q];
    out[0] = s * (1.0f / 16384.0f);
}

// ---------------------------------------------------------------------------
extern "C" void kernel_launch(void* const* d_in, const int* in_sizes, int n_in,
                              void* d_out, int out_size, void* d_ws, size_t ws_size,
                              hipStream_t stream)
{
    (void)in_sizes; (void)n_in; (void)out_size; (void)ws_size;

    const float* id_emb = (const float*)d_in[0];
    const float* feats[2] = { (const float*)d_in[1], (const float*)d_in[2] };
    const float* mw     = (const float*)d_in[3];
    const float* Wa[2]  = { (const float*)d_in[4],  (const float*)d_in[6]  };
    const float* ba[2]  = { (const float*)d_in[5],  (const float*)d_in[7]  };
    const float* W1[2]  = { (const float*)d_in[8],  (const float*)d_in[12] };
    const float* b1[2]  = { (const float*)d_in[9],  (const float*)d_in[13] };
    const float* W2[2]  = { (const float*)d_in[10], (const float*)d_in[14] };
    const float* b2[2]  = { (const float*)d_in[11], (const float*)d_in[15] };
    const int    Fdim[2] = { 768, 2048 };

    // Layout: X is NOT aliased (id half persists across modalities);
    // S (64 MB) aliases featb+H (both dead during the sim phase).
    char* p = (char*)d_ws;
    unsigned short* WaT   = (unsigned short*)p; p += (size_t)1024 * 2048 * 2;  //  4 MB
    unsigned short* W1T   = (unsigned short*)p; p += (size_t)1024 * 1024 * 2;  //  2 MB
    unsigned short* W2T   = (unsigned short*)p; p += (size_t)512  * 1024 * 2;  //  1 MB
    unsigned short* X     = (unsigned short*)p; p += (size_t)16384 * 1024 * 2; // 32 MB
    unsigned short* featb = (unsigned short*)p; p += (size_t)8192 * 2048 * 2;  // 32 MB
    unsigned short* H     = (unsigned short*)p; p += (size_t)16384 * 1024 * 2; // 32 MB
    unsigned short* PB    = (unsigned short*)p; p += (size_t)16384 * 512  * 2; // 16 MB
    float*          accum = (float*)p;          // 128 floats (2 x 64 slots)
    unsigned short* S     = featb;               // 4096x8192 bf16 = 64 MB

    zero_kernel<<<1, 128, 0, stream>>>(accum);

    // id embeddings -> bf16 lower half of X, once (X never aliased)
    cast_bf16_kernel<<<(8192 * 1024 / 4 + 255) / 256, 256, 0, stream>>>(
        id_emb, X + (size_t)8192 * 1024, 8192 * 1024 / 4);

    for (int m = 0; m < 2; ++m) {
        const int F = Fdim[m];

        cast_bf16_kernel<<<(8192 * F / 4 + 255) / 256, 256, 0, stream>>>(
            feats[m], featb, 8192 * F / 4);
        transpose_cast_kernel<<<dim3(1024 / 32, F / 32), 256, 0, stream>>>(
            Wa[m], WaT, F, 1024);
        transpose_cast_kernel<<<dim3(1024 / 32, 1024 / 32), 256, 0, stream>>>(
            W1[m], W1T, 1024, 1024);
        transpose_cast_kernel<<<dim3(512 / 32, 1024 / 32), 256, 0, stream>>>(
            W2[m], W2T, 1024, 512);

        // X[0:8192] = feat @ Wa + ba   (8192 x 1024, bf16)
        gemm_bt_mfma<<<(8192 / 128) * (1024 / 128), 256, 0, stream>>>(
            featb, F, WaT, F, X, 1024, 8192, 1024, F, ba[m], 0, 1.0f);

        // H = relu(X @ W1 + b1)        (16384 x 1024, bf16)
        gemm_bt_mfma<<<(16384 / 128) * (1024 / 128), 256, 0, stream>>>(
            X, 1024, W1T, 1024, H, 1024, 16384, 1024, 1024, b1[m], 1, 1.0f);
        // PB = H @ W2 + b2             (16384 x 512, bf16)
        gemm_bt_mfma<<<(16384 / 128) * (512 / 128), 256, 0, stream>>>(
            H, 1024, W2T, 1024, PB, 512, 16384, 512, 1024, b2[m], 0, 1.0f);
        // normalize in place           (modal rows 0:8192, id rows 8192:)
        normalize_bf16_kernel<<<16384, 128, 0, stream>>>(PB);

        const unsigned short* mproj = PB;
        const unsigned short* iproj = PB + (size_t)8192 * 512;

        for (int c = 0; c < 2; ++c) {
            // S = 10 * id_proj[chunk 4096] @ modal_proj^T  (4096 x 8192 bf16)
            gemm_bt_mfma<<<(4096 / 128) * (8192 / 128), 256, 0, stream>>>(
                iproj + (size_t)c * 4096 * 512, 512, mproj, 512,
                S, 8192, 4096, 8192, 512, nullptr, 0, 10.0f);
            row_loss_kernel<<<4096, 256, 0, stream>>>(
                S, c * 4096, mw, m, accum);
        }
    }

    finalize_kernel<<<1, 1, 0, stream>>>(accum, (float*)d_out);
}

// Round 6
// 709.124 us; speedup vs baseline: 1.1578x; 1.0731x over previous
//
#include <hip/hip_runtime.h>
#include <math.h>
#include <stdint.h>

// ---------------------------------------------------------------------------
// IntraModalContrastive loss. Round 12 (= Round 11 resubmit; infra failure):
//  - row_loss_kernel v6: 256 thr, raw-bf16 retention in 8 VGPRs, spread
//    accum atomics, __launch_bounds__(256,4). The earlier (256,8) bound
//    forced VGPR=32 and spilled the retained registers to scratch
//    (WRITE_SIZE 0.13->86 MB, dur 63->77 us). 128-VGPR cap removes the
//    spill while still allowing 8 blocks/CU if alloc <= 64.
//  - GEMM unchanged from Round 8 (128x128, BK=64, dbuf 2-phase, src-side
//    XOR swizzle, 1 barrier/K-tile).
// ---------------------------------------------------------------------------

typedef __attribute__((ext_vector_type(4))) float  floatx4;
typedef __attribute__((ext_vector_type(8))) __bf16 bf16x8;

__device__ __forceinline__ unsigned short f2bf(float f)
{
    unsigned u = __float_as_uint(f);
    unsigned r = (u + 0x7FFFu + ((u >> 16) & 1u)) >> 16;
    return (unsigned short)r;
}

__device__ __forceinline__ float bf2f(unsigned short u)
{
    return __uint_as_float((unsigned)u << 16);
}

__device__ __forceinline__ void gld_lds16(const void* g, void* l)
{
    __builtin_amdgcn_global_load_lds(
        (const __attribute__((address_space(1))) void*)g,
        (__attribute__((address_space(3))) void*)(uint32_t)(uintptr_t)l,
        16, 0, 0);
}

#define EPW 136   // epilogue LDS row stride in shorts (272 B, 16B-aligned)

// Stage one 128x64 bf16 tile (16 KB) global -> LDS, source-side swizzled:
// LDS chunk position p = row*8 + s holds global column-chunk c = s ^ (row&7).
// Dest is linear (wave-uniform base + lane*16) as global_load_lds requires.
__device__ __forceinline__ void stage_tile(
    const unsigned short* __restrict__ g, int ld, int k0,
    unsigned short* lds, int t)
{
#pragma unroll
    for (int it = 0; it < 4; ++it) {
        const int row = it * 32 + (t >> 3);
        const int c   = (t & 7) ^ ((t >> 3) & 7);     // == (t&7) ^ (row&7)
        gld_lds16(g + (size_t)row * ld + k0 + c * 8,
                  lds + (it * 256 + t) * 8);
    }
}

// ---------- bf16 MFMA GEMM: 128x128 tile, 256 thr, BK=64, dbuf ------------
// C[M,N] = ep(scale*(A @ B^T) + bias); A: MxK bf16 (lda), B: NxK bf16 (ldb).
// grid.x == (M/128)*(N/128), divisible by 8; M/128 divisible by 4;
// K divisible by 64.
__global__ __launch_bounds__(256) void gemm_bt_mfma(
    const unsigned short* __restrict__ A, int lda,
    const unsigned short* __restrict__ B, int ldb,
    unsigned short* __restrict__ C, int ldc, int M, int N, int K,
    const float* __restrict__ bias, int relu, float scale)
{
    // buf0: A [0,8192) B [8192,16384); buf1: A [16384,24576) B [24576,32768)
    // epilogue reuses [0, 128*EPW). Total = 65536 B (2 blocks/CU).
    __shared__ __align__(16) unsigned short smem[32768];

    const int num_n = N >> 7;
    const int per   = gridDim.x >> 3;
    const int pid   = blockIdx.x;
    const int npid  = (pid & 7) * per + (pid >> 3);   // XCD-contiguous
    const int width = 4 * num_n;
    const int group = npid / width;
    const int rem   = npid - group * width;
    const int pm    = group * 4 + (rem & 3);
    const int pn    = rem >> 2;

    const int t    = threadIdx.x;
    const int lane = t & 63;
    const int w    = t >> 6;        // 0..3
    const int wr   = w >> 1;        // 0..1 (64-row band)
    const int wc   = w & 1;         // 0..1 (64-col band)
    const size_t m0 = (size_t)pm * 128;
    const size_t n0 = (size_t)pn * 128;

    floatx4 acc[4][4] = {};

    const unsigned short* Abase = A + m0 * (size_t)lda;
    const unsigned short* Bbase = B + n0 * (size_t)ldb;

    // Loop-invariant swizzled fragment offsets (shorts, relative to buf base).
    // Fragment (row r, k-chunk c = ks*4 + lane>>4) lives at r*64 + (c^(r&7))*8.
    int aoff[4][2], boff[4][2];
#pragma unroll
    for (int i = 0; i < 4; ++i) {
        const int ra = wr * 64 + i * 16 + (lane & 15);
        const int rb = wc * 64 + i * 16 + (lane & 15);
#pragma unroll
        for (int ks = 0; ks < 2; ++ks) {
            const int cc = ks * 4 + (lane >> 4);
            aoff[i][ks] = ra * 64 + ((cc ^ (ra & 7)) << 3);
            boff[i][ks] = rb * 64 + ((cc ^ (rb & 7)) << 3);
        }
    }

    const int NT = K >> 6;

    // prologue: stage K-tile 0 into buf0, drain, barrier
    stage_tile(Abase, lda, 0, smem, t);
    stage_tile(Bbase, ldb, 0, smem + 8192, t);
    __syncthreads();

    int cur = 0;
    for (int kt = 0; kt < NT; ++kt) {
        // issue next tile's staging FIRST -> latency hides under compute
        if (kt + 1 < NT) {
            unsigned short* nb = smem + (cur ^ 1) * 16384;
            stage_tile(Abase, lda, (kt + 1) << 6, nb, t);
            stage_tile(Bbase, ldb, (kt + 1) << 6, nb + 8192, t);
        }

        const unsigned short* As = smem + cur * 16384;
        const unsigned short* Bs = As + 8192;

        bf16x8 af[4][2], bfr[4][2];
#pragma unroll
        for (int i = 0; i < 4; ++i) {
#pragma unroll
            for (int ks = 0; ks < 2; ++ks) {
                af[i][ks]  = *(const bf16x8*)(As + aoff[i][ks]);
                bfr[i][ks] = *(const bf16x8*)(Bs + boff[i][ks]);
            }
        }
#pragma unroll
        for (int i = 0; i < 4; ++i)
#pragma unroll
            for (int j = 0; j < 4; ++j)
#pragma unroll
                for (int ks = 0; ks < 2; ++ks)
                    acc[i][j] = __builtin_amdgcn_mfma_f32_16x16x32_bf16(
                        af[i][ks], bfr[j][ks], acc[i][j], 0, 0, 0);

        __syncthreads();   // drains prefetch vmcnt + barrier (once per K-tile)
        cur ^= 1;
    }

    // --- epilogue: one 128-row pass through LDS, coalesced uint4 stores ---
    const int col   = lane & 15;
    const int rquad = (lane >> 4) * 4;
#pragma unroll
    for (int j = 0; j < 4; ++j) {
        const int lc = wc * 64 + j * 16 + col;
        const float bv = bias ? bias[n0 + lc] : 0.0f;
#pragma unroll
        for (int i = 0; i < 4; ++i) {
            const int lr0 = wr * 64 + i * 16 + rquad;
#pragma unroll
            for (int r = 0; r < 4; ++r) {
                float v = acc[i][j][r] * scale + bv;
                if (relu) v = fmaxf(v, 0.0f);
                smem[(lr0 + r) * EPW + lc] = f2bf(v);
            }
        }
    }
    __syncthreads();
#pragma unroll
    for (int h = 0; h < 2; ++h) {
        const int cr = h * 64 + (t >> 2);   // 0..127
        const int cq = t & 3;
#pragma unroll
        for (int q = 0; q < 4; ++q) {
            const int chunk = cq + q * 4;           // 0..15
            uint4 v = *(const uint4*)(smem + cr * EPW + chunk * 8);
            *(uint4*)(C + (m0 + cr) * (size_t)ldc + n0 + chunk * 8) = v;
        }
    }
}

// ---------- elementwise fp32 -> bf16 cast -----------------------------------
__global__ __launch_bounds__(256) void cast_bf16_kernel(
    const float* __restrict__ in, unsigned short* __restrict__ out, int n4)
{
    const int i = blockIdx.x * 256 + threadIdx.x;
    if (i < n4) {
        float4 v = *(const float4*)(in + (size_t)i * 4);
        ushort4 o;
        o.x = f2bf(v.x); o.y = f2bf(v.y); o.z = f2bf(v.z); o.w = f2bf(v.w);
        *(ushort4*)(out + (size_t)i * 4) = o;
    }
}

// ---------- transpose + cast: W[K,N] fp32 -> WT[N,K] bf16 -------------------
__global__ __launch_bounds__(256) void transpose_cast_kernel(
    const float* __restrict__ W, unsigned short* __restrict__ WT, int K, int N)
{
    __shared__ float tile[32][33];
    const int k0 = blockIdx.y * 32;
    const int n0 = blockIdx.x * 32;
    const int tr = threadIdx.x >> 3;
    const int tc = (threadIdx.x & 7) * 4;

    float4 v = *(const float4*)(W + (size_t)(k0 + tr) * N + n0 + tc);
    tile[tr][tc + 0] = v.x;
    tile[tr][tc + 1] = v.y;
    tile[tr][tc + 2] = v.z;
    tile[tr][tc + 3] = v.w;
    __syncthreads();

    ushort4 o;
    o.x = f2bf(tile[tc + 0][tr]);
    o.y = f2bf(tile[tc + 1][tr]);
    o.z = f2bf(tile[tc + 2][tr]);
    o.w = f2bf(tile[tc + 3][tr]);
    *(ushort4*)(WT + (size_t)(n0 + tr) * K + k0 + tc) = o;
}

// ---------- row L2-normalize, bf16 in-place, width 512 ----------------------
__global__ __launch_bounds__(128) void normalize_bf16_kernel(
    unsigned short* __restrict__ X)
{
    const int r = blockIdx.x;
    const int t = threadIdx.x;
    unsigned short* row = X + (size_t)r * 512;
    ushort4 u = *(const ushort4*)(row + t * 4);
    float x0 = bf2f(u.x), x1 = bf2f(u.y), x2 = bf2f(u.z), x3 = bf2f(u.w);
    float ss = x0 * x0 + x1 * x1 + x2 * x2 + x3 * x3;
#pragma unroll
    for (int off = 32; off > 0; off >>= 1) ss += __shfl_down(ss, off, 64);
    __shared__ float sred[2];
    if ((t & 63) == 0) sred[t >> 6] = ss;
    __syncthreads();
    float inv = 1.0f / sqrtf(sred[0] + sred[1]);
    ushort4 o;
    o.x = f2bf(x0 * inv); o.y = f2bf(x1 * inv);
    o.z = f2bf(x2 * inv); o.w = f2bf(x3 * inv);
    *(ushort4*)(row + t * 4) = o;
}

// ---------- per-row mining + loss (v6: 256 thr, raw-reg retention) ----------
// accum is a 2x64 float array; each block adds into slot [midx*64 + blk&63].
__global__ __launch_bounds__(256, 4) void row_loss_kernel(
    const unsigned short* __restrict__ S, int row_base,
    const float* __restrict__ mw, int midx, float* __restrict__ accum)
{
    __shared__ unsigned hist[4096];         // 16 KB
    __shared__ unsigned wtot[4];
    __shared__ float fred[4];
    __shared__ unsigned sh_b;
    __shared__ float sh_diag;

    const int t    = threadIdx.x;           // 0..255
    const int lane = t & 63;
    const int wv   = t >> 6;                // 0..3
    const int i    = row_base + blockIdx.x; // diag column index
    const unsigned short* Srow = S + (size_t)blockIdx.x * 8192;

    for (int b = t; b < 4096; b += 256) hist[b] = 0;

    // single global read: 32 elements as raw bf16 in 8 VGPRs.
    // segment seg (0..3) covers columns seg*2048 + t*8 .. +7.
    uint4 raw[4];
#pragma unroll
    for (int seg = 0; seg < 4; ++seg)
        raw[seg] = *(const uint4*)(Srow + seg * 2048 + t * 8);
    __syncthreads();     // hist zeroed

#pragma unroll
    for (int seg = 0; seg < 4; ++seg) {
        const unsigned short* e = (const unsigned short*)&raw[seg];
#pragma unroll
        for (int q = 0; q < 8; ++q) {
            const int j = seg * 2048 + t * 8 + q;
            const float s = bf2f(e[q]);
            if (j != i && s <= 9.0f) {
                int k = (int)((s + 10.25f) * 200.0f);
                k = k < 1 ? 1 : (k > 4095 ? 4095 : k);
                atomicAdd(&hist[k], 1u);
            }
        }
    }
    __syncthreads();

    // suffix-sum over 4096 bins; thread t owns bins [t*16, t*16+16)
    unsigned local = 0;
#pragma unroll
    for (int q = 0; q < 16; ++q) local += hist[t * 16 + q];
    unsigned suf = local;
#pragma unroll
    for (int off = 1; off < 64; off <<= 1) {
        unsigned v = __shfl_down(suf, off, 64);
        if (lane + off < 64) suf += v;
    }
    if (lane == 0) wtot[wv] = suf;
    __syncthreads();
    unsigned wsuf = 0;
#pragma unroll
    for (int q = 0; q < 4; ++q) wsuf += (q > wv) ? wtot[q] : 0u;
    suf += wsuf;

    const unsigned target = 4096;
    const unsigned above  = suf - local;
    if (suf >= target && above < target) {
        unsigned cum = above;
        int bsel = t * 16;
#pragma unroll
        for (int q = 15; q >= 0; --q) {
            unsigned c = hist[t * 16 + q];
            if (cum + c >= target) { bsel = t * 16 + q; break; }
            cum += c;
        }
        sh_b = (unsigned)bsel;
    }
    if (t == 0 && suf < target) sh_b = 1u;
    __syncthreads();
    const unsigned bsel = sh_b;

    float lsum = 0.0f;
#pragma unroll
    for (int seg = 0; seg < 4; ++seg) {
        const unsigned short* e = (const unsigned short*)&raw[seg];
#pragma unroll
        for (int q = 0; q < 8; ++q) {
            const int j = seg * 2048 + t * 8 + q;
            const float s = bf2f(e[q]);
            bool diag  = (j == i);
            bool noise = (!diag && s > 9.0f);
            int k = (int)((s + 10.25f) * 200.0f);
            k = k < 1 ? 1 : (k > 4095 ? 4095 : k);
            bool hard = !diag && !noise && ((unsigned)k >= bsel);
            float wgt = noise ? 0.5f : (hard ? 1.5f : 1.0f);
            float ws = s * wgt;
            if (diag) sh_diag = ws;
            lsum += __expf(ws - 16.0f);
        }
    }
#pragma unroll
    for (int off = 32; off > 0; off >>= 1)
        lsum += __shfl_down(lsum, off, 64);
    if (lane == 0) fred[wv] = lsum;
    __syncthreads();
    if (t == 0) {
        float total = fred[0] + fred[1] + fred[2] + fred[3];
        float lse = 16.0f + logf(total);
        float ce = lse - sh_diag;
        atomicAdd(&accum[midx * 64 + (blockIdx.x & 63)],
                  ce * mw[(size_t)i * 2 + midx]);
    }
}

__global__ void zero_kernel(float* __restrict__ accum)
{
    if (threadIdx.x < 128) accum[threadIdx.x] = 0.0f;
}

__global__ void finalize_kernel(const float* __restrict__ accum,
                                float* __restrict__ out)
{
    float s = 0.0f;
    for (int q = 0; q < 128; ++q) s += accum[q];
    out[0] = s * (1.0f / 16384.0f);
}

// ---------------------------------------------------------------------------
extern "C" void kernel_launch(void* const* d_in, const int* in_sizes, int n_in,
                              void* d_out, int out_size, void* d_ws, size_t ws_size,
                              hipStream_t stream)
{
    (void)in_sizes; (void)n_in; (void)out_size; (void)ws_size;

    const float* id_emb = (const float*)d_in[0];
    const float* feats[2] = { (const float*)d_in[1], (const float*)d_in[2] };
    const float* mw     = (const float*)d_in[3];
    const float* Wa[2]  = { (const float*)d_in[4],  (const float*)d_in[6]  };
    const float* ba[2]  = { (const float*)d_in[5],  (const float*)d_in[7]  };
    const float* W1[2]  = { (const float*)d_in[8],  (const float*)d_in[12] };
    const float* b1[2]  = { (const float*)d_in[9],  (const float*)d_in[13] };
    const float* W2[2]  = { (const float*)d_in[10], (const float*)d_in[14] };
    const float* b2[2]  = { (const float*)d_in[11], (const float*)d_in[15] };
    const int    Fdim[2] = { 768, 2048 };

    // Layout: X is NOT aliased (id half persists across modalities);
    // S (64 MB) aliases featb+H (both dead during the sim phase).
    char* p = (char*)d_ws;
    unsigned short* WaT   = (unsigned short*)p; p += (size_t)1024 * 2048 * 2;  //  4 MB
    unsigned short* W1T   = (unsigned short*)p; p += (size_t)1024 * 1024 * 2;  //  2 MB
    unsigned short* W2T   = (unsigned short*)p; p += (size_t)512  * 1024 * 2;  //  1 MB
    unsigned short* X     = (unsigned short*)p; p += (size_t)16384 * 1024 * 2; // 32 MB
    unsigned short* featb = (unsigned short*)p; p += (size_t)8192 * 2048 * 2;  // 32 MB
    unsigned short* H     = (unsigned short*)p; p += (size_t)16384 * 1024 * 2; // 32 MB
    unsigned short* PB    = (unsigned short*)p; p += (size_t)16384 * 512  * 2; // 16 MB
    float*          accum = (float*)p;          // 128 floats (2 x 64 slots)
    unsigned short* S     = featb;               // 4096x8192 bf16 = 64 MB

    zero_kernel<<<1, 128, 0, stream>>>(accum);

    // id embeddings -> bf16 lower half of X, once (X never aliased)
    cast_bf16_kernel<<<(8192 * 1024 / 4 + 255) / 256, 256, 0, stream>>>(
        id_emb, X + (size_t)8192 * 1024, 8192 * 1024 / 4);

    for (int m = 0; m < 2; ++m) {
        const int F = Fdim[m];

        cast_bf16_kernel<<<(8192 * F / 4 + 255) / 256, 256, 0, stream>>>(
            feats[m], featb, 8192 * F / 4);
        transpose_cast_kernel<<<dim3(1024 / 32, F / 32), 256, 0, stream>>>(
            Wa[m], WaT, F, 1024);
        transpose_cast_kernel<<<dim3(1024 / 32, 1024 / 32), 256, 0, stream>>>(
            W1[m], W1T, 1024, 1024);
        transpose_cast_kernel<<<dim3(512 / 32, 1024 / 32), 256, 0, stream>>>(
            W2[m], W2T, 1024, 512);

        // X[0:8192] = feat @ Wa + ba   (8192 x 1024, bf16)
        gemm_bt_mfma<<<(8192 / 128) * (1024 / 128), 256, 0, stream>>>(
            featb, F, WaT, F, X, 1024, 8192, 1024, F, ba[m], 0, 1.0f);

        // H = relu(X @ W1 + b1)        (16384 x 1024, bf16)
        gemm_bt_mfma<<<(16384 / 128) * (1024 / 128), 256, 0, stream>>>(
            X, 1024, W1T, 1024, H, 1024, 16384, 1024, 1024, b1[m], 1, 1.0f);
        // PB = H @ W2 + b2             (16384 x 512, bf16)
        gemm_bt_mfma<<<(16384 / 128) * (512 / 128), 256, 0, stream>>>(
            H, 1024, W2T, 1024, PB, 512, 16384, 512, 1024, b2[m], 0, 1.0f);
        // normalize in place           (modal rows 0:8192, id rows 8192:)
        normalize_bf16_kernel<<<16384, 128, 0, stream>>>(PB);

        const unsigned short* mproj = PB;
        const unsigned short* iproj = PB + (size_t)8192 * 512;

        for (int c = 0; c < 2; ++c) {
            // S = 10 * id_proj[chunk 4096] @ modal_proj^T  (4096 x 8192 bf16)
            gemm_bt_mfma<<<(4096 / 128) * (8192 / 128), 256, 0, stream>>>(
                iproj + (size_t)c * 4096 * 512, 512, mproj, 512,
                S, 8192, 4096, 8192, 512, nullptr, 0, 10.0f);
            row_loss_kernel<<<4096, 256, 0, stream>>>(
                S, c * 4096, mw, m, accum);
        }
    }

    finalize_kernel<<<1, 1, 0, stream>>>(accum, (float*)d_out);
}

// Round 7
// 707.546 us; speedup vs baseline: 1.1604x; 1.0022x over previous
//
#include <hip/hip_runtime.h>
#include <math.h>
#include <stdint.h>

// ---------------------------------------------------------------------------
// IntraModalContrastive loss. Round 13:
//  - GEMM K-loop upgraded to counted-vmcnt pipeline (T3/T4 minimum form):
//    stage next tile FIRST, s_waitcnt vmcnt(8) (prefetch loads stay in
//    flight ACROSS the barrier), raw s_barrier, ds_read+MFMA, lgkmcnt(0)
//    + s_barrier (anti-overwrite). No vmcnt(0) drain in steady state.
//    Previous __syncthreads() drained the just-issued prefetch every
//    iteration -> ~50% stall (MfmaUtil 23%).
//  - row_loss v6 unchanged (256 thr, reg retention, (256,4) bounds).
// ---------------------------------------------------------------------------

typedef __attribute__((ext_vector_type(4))) float  floatx4;
typedef __attribute__((ext_vector_type(8))) __bf16 bf16x8;

__device__ __forceinline__ unsigned short f2bf(float f)
{
    unsigned u = __float_as_uint(f);
    unsigned r = (u + 0x7FFFu + ((u >> 16) & 1u)) >> 16;
    return (unsigned short)r;
}

__device__ __forceinline__ float bf2f(unsigned short u)
{
    return __uint_as_float((unsigned)u << 16);
}

__device__ __forceinline__ void gld_lds16(const void* g, void* l)
{
    __builtin_amdgcn_global_load_lds(
        (const __attribute__((address_space(1))) void*)g,
        (__attribute__((address_space(3))) void*)(uint32_t)(uintptr_t)l,
        16, 0, 0);
}

#define EPW 136   // epilogue LDS row stride in shorts (272 B, 16B-aligned)

// Stage one 128x64 bf16 tile (16 KB) global -> LDS, source-side swizzled:
// LDS chunk position p = row*8 + s holds global column-chunk c = s ^ (row&7).
// Dest is linear (wave-uniform base + lane*16) as global_load_lds requires.
// 4 vmem ops per thread.
__device__ __forceinline__ void stage_tile(
    const unsigned short* __restrict__ g, int ld, int k0,
    unsigned short* lds, int t)
{
#pragma unroll
    for (int it = 0; it < 4; ++it) {
        const int row = it * 32 + (t >> 3);
        const int c   = (t & 7) ^ ((t >> 3) & 7);     // == (t&7) ^ (row&7)
        gld_lds16(g + (size_t)row * ld + k0 + c * 8,
                  lds + (it * 256 + t) * 8);
    }
}

// ---------- bf16 MFMA GEMM: 128x128 tile, 256 thr, BK=64, counted vmcnt ----
// C[M,N] = ep(scale*(A @ B^T) + bias); A: MxK bf16 (lda), B: NxK bf16 (ldb).
// grid.x == (M/128)*(N/128), divisible by 8; M/128 divisible by 4;
// K divisible by 64, K >= 128.
__global__ __launch_bounds__(256) void gemm_bt_mfma(
    const unsigned short* __restrict__ A, int lda,
    const unsigned short* __restrict__ B, int ldb,
    unsigned short* __restrict__ C, int ldc, int M, int N, int K,
    const float* __restrict__ bias, int relu, float scale)
{
    // buf0: A [0,8192) B [8192,16384); buf1: A [16384,24576) B [24576,32768)
    // epilogue reuses [0, 128*EPW). Total = 65536 B (2 blocks/CU).
    __shared__ __align__(16) unsigned short smem[32768];

    const int num_n = N >> 7;
    const int per   = gridDim.x >> 3;
    const int pid   = blockIdx.x;
    const int npid  = (pid & 7) * per + (pid >> 3);   // XCD-contiguous
    const int width = 4 * num_n;
    const int group = npid / width;
    const int rem   = npid - group * width;
    const int pm    = group * 4 + (rem & 3);
    const int pn    = rem >> 2;

    const int t    = threadIdx.x;
    const int lane = t & 63;
    const int w    = t >> 6;        // 0..3
    const int wr   = w >> 1;        // 0..1 (64-row band)
    const int wc   = w & 1;         // 0..1 (64-col band)
    const size_t m0 = (size_t)pm * 128;
    const size_t n0 = (size_t)pn * 128;

    floatx4 acc[4][4] = {};

    const unsigned short* Abase = A + m0 * (size_t)lda;
    const unsigned short* Bbase = B + n0 * (size_t)ldb;

    // Loop-invariant swizzled fragment offsets (shorts, relative to buf base).
    // Fragment (row r, k-chunk c = ks*4 + lane>>4) lives at r*64 + (c^(r&7))*8.
    int aoff[4][2], boff[4][2];
#pragma unroll
    for (int i = 0; i < 4; ++i) {
        const int ra = wr * 64 + i * 16 + (lane & 15);
        const int rb = wc * 64 + i * 16 + (lane & 15);
#pragma unroll
        for (int ks = 0; ks < 2; ++ks) {
            const int cc = ks * 4 + (lane >> 4);
            aoff[i][ks] = ra * 64 + ((cc ^ (ra & 7)) << 3);
            boff[i][ks] = rb * 64 + ((cc ^ (rb & 7)) << 3);
        }
    }

    const int NT = K >> 6;

    // prologue: issue K-tile 0 staging (8 vmem); NO drain here — iteration 0
    // performs the counted wait itself.
    stage_tile(Abase, lda, 0, smem, t);
    stage_tile(Bbase, ldb, 0, smem + 8192, t);

    int cur = 0;
    for (int kt = 0; kt < NT; ++kt) {
        // Issue next tile's 8 loads FIRST, then wait only for the CURRENT
        // tile (vmcnt(8) leaves the 8 prefetch loads in flight across the
        // barrier). Invariant at loop top: exactly 8 outstanding (tile kt).
        if (kt + 1 < NT) {
            unsigned short* nb = smem + (cur ^ 1) * 16384;
            stage_tile(Abase, lda, (kt + 1) << 6, nb, t);
            stage_tile(Bbase, ldb, (kt + 1) << 6, nb + 8192, t);
            asm volatile("s_waitcnt vmcnt(8)" ::: "memory");
        } else {
            asm volatile("s_waitcnt vmcnt(0)" ::: "memory");
        }
        __builtin_amdgcn_sched_barrier(0);
        __builtin_amdgcn_s_barrier();      // tile kt visible to all waves
        __builtin_amdgcn_sched_barrier(0);

        const unsigned short* As = smem + cur * 16384;
        const unsigned short* Bs = As + 8192;

        bf16x8 af[4][2], bfr[4][2];
#pragma unroll
        for (int i = 0; i < 4; ++i) {
#pragma unroll
            for (int ks = 0; ks < 2; ++ks) {
                af[i][ks]  = *(const bf16x8*)(As + aoff[i][ks]);
                bfr[i][ks] = *(const bf16x8*)(Bs + boff[i][ks]);
            }
        }
#pragma unroll
        for (int i = 0; i < 4; ++i)
#pragma unroll
            for (int j = 0; j < 4; ++j)
#pragma unroll
                for (int ks = 0; ks < 2; ++ks)
                    acc[i][j] = __builtin_amdgcn_mfma_f32_16x16x32_bf16(
                        af[i][ks], bfr[j][ks], acc[i][j], 0, 0, 0);

        // all ds_reads of buf[cur] complete in every thread before any
        // thread may overwrite it next iteration (stage targets buf[cur]).
        asm volatile("s_waitcnt lgkmcnt(0)" ::: "memory");
        __builtin_amdgcn_sched_barrier(0);
        __builtin_amdgcn_s_barrier();
        __builtin_amdgcn_sched_barrier(0);
        cur ^= 1;
    }

    // --- epilogue: one 128-row pass through LDS, coalesced uint4 stores ---
    const int col   = lane & 15;
    const int rquad = (lane >> 4) * 4;
#pragma unroll
    for (int j = 0; j < 4; ++j) {
        const int lc = wc * 64 + j * 16 + col;
        const float bv = bias ? bias[n0 + lc] : 0.0f;
#pragma unroll
        for (int i = 0; i < 4; ++i) {
            const int lr0 = wr * 64 + i * 16 + rquad;
#pragma unroll
            for (int r = 0; r < 4; ++r) {
                float v = acc[i][j][r] * scale + bv;
                if (relu) v = fmaxf(v, 0.0f);
                smem[(lr0 + r) * EPW + lc] = f2bf(v);
            }
        }
    }
    __syncthreads();
#pragma unroll
    for (int h = 0; h < 2; ++h) {
        const int cr = h * 64 + (t >> 2);   // 0..127
        const int cq = t & 3;
#pragma unroll
        for (int q = 0; q < 4; ++q) {
            const int chunk = cq + q * 4;           // 0..15
            uint4 v = *(const uint4*)(smem + cr * EPW + chunk * 8);
            *(uint4*)(C + (m0 + cr) * (size_t)ldc + n0 + chunk * 8) = v;
        }
    }
}

// ---------- elementwise fp32 -> bf16 cast -----------------------------------
__global__ __launch_bounds__(256) void cast_bf16_kernel(
    const float* __restrict__ in, unsigned short* __restrict__ out, int n4)
{
    const int i = blockIdx.x * 256 + threadIdx.x;
    if (i < n4) {
        float4 v = *(const float4*)(in + (size_t)i * 4);
        ushort4 o;
        o.x = f2bf(v.x); o.y = f2bf(v.y); o.z = f2bf(v.z); o.w = f2bf(v.w);
        *(ushort4*)(out + (size_t)i * 4) = o;
    }
}

// ---------- transpose + cast: W[K,N] fp32 -> WT[N,K] bf16 -------------------
__global__ __launch_bounds__(256) void transpose_cast_kernel(
    const float* __restrict__ W, unsigned short* __restrict__ WT, int K, int N)
{
    __shared__ float tile[32][33];
    const int k0 = blockIdx.y * 32;
    const int n0 = blockIdx.x * 32;
    const int tr = threadIdx.x >> 3;
    const int tc = (threadIdx.x & 7) * 4;

    float4 v = *(const float4*)(W + (size_t)(k0 + tr) * N + n0 + tc);
    tile[tr][tc + 0] = v.x;
    tile[tr][tc + 1] = v.y;
    tile[tr][tc + 2] = v.z;
    tile[tr][tc + 3] = v.w;
    __syncthreads();

    ushort4 o;
    o.x = f2bf(tile[tc + 0][tr]);
    o.y = f2bf(tile[tc + 1][tr]);
    o.z = f2bf(tile[tc + 2][tr]);
    o.w = f2bf(tile[tc + 3][tr]);
    *(ushort4*)(WT + (size_t)(n0 + tr) * K + k0 + tc) = o;
}

// ---------- row L2-normalize, bf16 in-place, width 512 ----------------------
__global__ __launch_bounds__(128) void normalize_bf16_kernel(
    unsigned short* __restrict__ X)
{
    const int r = blockIdx.x;
    const int t = threadIdx.x;
    unsigned short* row = X + (size_t)r * 512;
    ushort4 u = *(const ushort4*)(row + t * 4);
    float x0 = bf2f(u.x), x1 = bf2f(u.y), x2 = bf2f(u.z), x3 = bf2f(u.w);
    float ss = x0 * x0 + x1 * x1 + x2 * x2 + x3 * x3;
#pragma unroll
    for (int off = 32; off > 0; off >>= 1) ss += __shfl_down(ss, off, 64);
    __shared__ float sred[2];
    if ((t & 63) == 0) sred[t >> 6] = ss;
    __syncthreads();
    float inv = 1.0f / sqrtf(sred[0] + sred[1]);
    ushort4 o;
    o.x = f2bf(x0 * inv); o.y = f2bf(x1 * inv);
    o.z = f2bf(x2 * inv); o.w = f2bf(x3 * inv);
    *(ushort4*)(row + t * 4) = o;
}

// ---------- per-row mining + loss (v6: 256 thr, raw-reg retention) ----------
// accum is a 2x64 float array; each block adds into slot [midx*64 + blk&63].
__global__ __launch_bounds__(256, 4) void row_loss_kernel(
    const unsigned short* __restrict__ S, int row_base,
    const float* __restrict__ mw, int midx, float* __restrict__ accum)
{
    __shared__ unsigned hist[4096];         // 16 KB
    __shared__ unsigned wtot[4];
    __shared__ float fred[4];
    __shared__ unsigned sh_b;
    __shared__ float sh_diag;

    const int t    = threadIdx.x;           // 0..255
    const int lane = t & 63;
    const int wv   = t >> 6;                // 0..3
    const int i    = row_base + blockIdx.x; // diag column index
    const unsigned short* Srow = S + (size_t)blockIdx.x * 8192;

    for (int b = t; b < 4096; b += 256) hist[b] = 0;

    // single global read: 32 elements as raw bf16 in 8 VGPRs.
    // segment seg (0..3) covers columns seg*2048 + t*8 .. +7.
    uint4 raw[4];
#pragma unroll
    for (int seg = 0; seg < 4; ++seg)
        raw[seg] = *(const uint4*)(Srow + seg * 2048 + t * 8);
    __syncthreads();     // hist zeroed

#pragma unroll
    for (int seg = 0; seg < 4; ++seg) {
        const unsigned short* e = (const unsigned short*)&raw[seg];
#pragma unroll
        for (int q = 0; q < 8; ++q) {
            const int j = seg * 2048 + t * 8 + q;
            const float s = bf2f(e[q]);
            if (j != i && s <= 9.0f) {
                int k = (int)((s + 10.25f) * 200.0f);
                k = k < 1 ? 1 : (k > 4095 ? 4095 : k);
                atomicAdd(&hist[k], 1u);
            }
        }
    }
    __syncthreads();

    // suffix-sum over 4096 bins; thread t owns bins [t*16, t*16+16)
    unsigned local = 0;
#pragma unroll
    for (int q = 0; q < 16; ++q) local += hist[t * 16 + q];
    unsigned suf = local;
#pragma unroll
    for (int off = 1; off < 64; off <<= 1) {
        unsigned v = __shfl_down(suf, off, 64);
        if (lane + off < 64) suf += v;
    }
    if (lane == 0) wtot[wv] = suf;
    __syncthreads();
    unsigned wsuf = 0;
#pragma unroll
    for (int q = 0; q < 4; ++q) wsuf += (q > wv) ? wtot[q] : 0u;
    suf += wsuf;

    const unsigned target = 4096;
    const unsigned above  = suf - local;
    if (suf >= target && above < target) {
        unsigned cum = above;
        int bsel = t * 16;
#pragma unroll
        for (int q = 15; q >= 0; --q) {
            unsigned c = hist[t * 16 + q];
            if (cum + c >= target) { bsel = t * 16 + q; break; }
            cum += c;
        }
        sh_b = (unsigned)bsel;
    }
    if (t == 0 && suf < target) sh_b = 1u;
    __syncthreads();
    const unsigned bsel = sh_b;

    float lsum = 0.0f;
#pragma unroll
    for (int seg = 0; seg < 4; ++seg) {
        const unsigned short* e = (const unsigned short*)&raw[seg];
#pragma unroll
        for (int q = 0; q < 8; ++q) {
            const int j = seg * 2048 + t * 8 + q;
            const float s = bf2f(e[q]);
            bool diag  = (j == i);
            bool noise = (!diag && s > 9.0f);
            int k = (int)((s + 10.25f) * 200.0f);
            k = k < 1 ? 1 : (k > 4095 ? 4095 : k);
            bool hard = !diag && !noise && ((unsigned)k >= bsel);
            float wgt = noise ? 0.5f : (hard ? 1.5f : 1.0f);
            float ws = s * wgt;
            if (diag) sh_diag = ws;
            lsum += __expf(ws - 16.0f);
        }
    }
#pragma unroll
    for (int off = 32; off > 0; off >>= 1)
        lsum += __shfl_down(lsum, off, 64);
    if (lane == 0) fred[wv] = lsum;
    __syncthreads();
    if (t == 0) {
        float total = fred[0] + fred[1] + fred[2] + fred[3];
        float lse = 16.0f + logf(total);
        float ce = lse - sh_diag;
        atomicAdd(&accum[midx * 64 + (blockIdx.x & 63)],
                  ce * mw[(size_t)i * 2 + midx]);
    }
}

__global__ void zero_kernel(float* __restrict__ accum)
{
    if (threadIdx.x < 128) accum[threadIdx.x] = 0.0f;
}

__global__ void finalize_kernel(const float* __restrict__ accum,
                                float* __restrict__ out)
{
    float s = 0.0f;
    for (int q = 0; q < 128; ++q) s += accum[q];
    out[0] = s * (1.0f / 16384.0f);
}

// ---------------------------------------------------------------------------
extern "C" void kernel_launch(void* const* d_in, const int* in_sizes, int n_in,
                              void* d_out, int out_size, void* d_ws, size_t ws_size,
                              hipStream_t stream)
{
    (void)in_sizes; (void)n_in; (void)out_size; (void)ws_size;

    const float* id_emb = (const float*)d_in[0];
    const float* feats[2] = { (const float*)d_in[1], (const float*)d_in[2] };
    const float* mw     = (const float*)d_in[3];
    const float* Wa[2]  = { (const float*)d_in[4],  (const float*)d_in[6]  };
    const float* ba[2]  = { (const float*)d_in[5],  (const float*)d_in[7]  };
    const float* W1[2]  = { (const float*)d_in[8],  (const float*)d_in[12] };
    const float* b1[2]  = { (const float*)d_in[9],  (const float*)d_in[13] };
    const float* W2[2]  = { (const float*)d_in[10], (const float*)d_in[14] };
    const float* b2[2]  = { (const float*)d_in[11], (const float*)d_in[15] };
    const int    Fdim[2] = { 768, 2048 };

    // Layout: X is NOT aliased (id half persists across modalities);
    // S (64 MB) aliases featb+H (both dead during the sim phase).
    char* p = (char*)d_ws;
    unsigned short* WaT   = (unsigned short*)p; p += (size_t)1024 * 2048 * 2;  //  4 MB
    unsigned short* W1T   = (unsigned short*)p; p += (size_t)1024 * 1024 * 2;  //  2 MB
    unsigned short* W2T   = (unsigned short*)p; p += (size_t)512  * 1024 * 2;  //  1 MB
    unsigned short* X     = (unsigned short*)p; p += (size_t)16384 * 1024 * 2; // 32 MB
    unsigned short* featb = (unsigned short*)p; p += (size_t)8192 * 2048 * 2;  // 32 MB
    unsigned short* H     = (unsigned short*)p; p += (size_t)16384 * 1024 * 2; // 32 MB
    unsigned short* PB    = (unsigned short*)p; p += (size_t)16384 * 512  * 2; // 16 MB
    float*          accum = (float*)p;          // 128 floats (2 x 64 slots)
    unsigned short* S     = featb;               // 4096x8192 bf16 = 64 MB

    zero_kernel<<<1, 128, 0, stream>>>(accum);

    // id embeddings -> bf16 lower half of X, once (X never aliased)
    cast_bf16_kernel<<<(8192 * 1024 / 4 + 255) / 256, 256, 0, stream>>>(
        id_emb, X + (size_t)8192 * 1024, 8192 * 1024 / 4);

    for (int m = 0; m < 2; ++m) {
        const int F = Fdim[m];

        cast_bf16_kernel<<<(8192 * F / 4 + 255) / 256, 256, 0, stream>>>(
            feats[m], featb, 8192 * F / 4);
        transpose_cast_kernel<<<dim3(1024 / 32, F / 32), 256, 0, stream>>>(
            Wa[m], WaT, F, 1024);
        transpose_cast_kernel<<<dim3(1024 / 32, 1024 / 32), 256, 0, stream>>>(
            W1[m], W1T, 1024, 1024);
        transpose_cast_kernel<<<dim3(512 / 32, 1024 / 32), 256, 0, stream>>>(
            W2[m], W2T, 1024, 512);

        // X[0:8192] = feat @ Wa + ba   (8192 x 1024, bf16)
        gemm_bt_mfma<<<(8192 / 128) * (1024 / 128), 256, 0, stream>>>(
            featb, F, WaT, F, X, 1024, 8192, 1024, F, ba[m], 0, 1.0f);

        // H = relu(X @ W1 + b1)        (16384 x 1024, bf16)
        gemm_bt_mfma<<<(16384 / 128) * (1024 / 128), 256, 0, stream>>>(
            X, 1024, W1T, 1024, H, 1024, 16384, 1024, 1024, b1[m], 1, 1.0f);
        // PB = H @ W2 + b2             (16384 x 512, bf16)
        gemm_bt_mfma<<<(16384 / 128) * (512 / 128), 256, 0, stream>>>(
            H, 1024, W2T, 1024, PB, 512, 16384, 512, 1024, b2[m], 0, 1.0f);
        // normalize in place           (modal rows 0:8192, id rows 8192:)
        normalize_bf16_kernel<<<16384, 128, 0, stream>>>(PB);

        const unsigned short* mproj = PB;
        const unsigned short* iproj = PB + (size_t)8192 * 512;

        for (int c = 0; c < 2; ++c) {
            // S = 10 * id_proj[chunk 4096] @ modal_proj^T  (4096 x 8192 bf16)
            gemm_bt_mfma<<<(4096 / 128) * (8192 / 128), 256, 0, stream>>>(
                iproj + (size_t)c * 4096 * 512, 512, mproj, 512,
                S, 8192, 4096, 8192, 512, nullptr, 0, 10.0f);
            row_loss_kernel<<<4096, 256, 0, stream>>>(
                S, c * 4096, mw, m, accum);
        }
    }

    finalize_kernel<<<1, 1, 0, stream>>>(accum, (float*)d_out);
}